// Round 5
// baseline (305.540 us; speedup 1.0000x reference)
//
#include <hip/hip_runtime.h>

typedef __attribute__((ext_vector_type(8))) short short8;
typedef __attribute__((ext_vector_type(4))) float f32x4;

__device__ inline float bf2f(unsigned short u) {
    return __uint_as_float(((unsigned int)u) << 16);
}
__device__ inline unsigned short f2bf(float f) {
    unsigned int x = __float_as_uint(f);
    return (unsigned short)((x + 0x7fffu + ((x >> 16) & 1u)) >> 16);
}

template<bool F32>
__device__ inline float loadf(const void* p, long i) {
    return F32 ? ((const float*)p)[i] : bf2f(((const unsigned short*)p)[i]);
}
template<bool F32>
__device__ inline short8 load8(const void* p, long i) {  // i % 8 == 0 at all call sites
    short8 r;
    if (F32) {
        const float* fp = (const float*)p + i;
        f32x4 a = *(const f32x4*)fp;
        f32x4 b = *(const f32x4*)(fp + 4);
#pragma unroll
        for (int j = 0; j < 4; ++j) { r[j] = (short)f2bf(a[j]); r[4 + j] = (short)f2bf(b[j]); }
    } else {
        r = *(const short8*)((const unsigned short*)p + i);
    }
    return r;
}

// per-block dtype detect on x (nonzero random data): fp32 -> low ushort of each word
// has ~uniform bf16-exponent field -> ~32/256 words hit exp>=0xE0; bf16 data -> 0 hits.
#define DETECT_F32(xptr, result)                                        \
    {                                                                   \
        __shared__ int s_cnt;                                           \
        if (threadIdx.x == 0) s_cnt = 0;                                \
        __syncthreads();                                                \
        if (threadIdx.x < 256) {                                        \
            unsigned int wrd = ((const unsigned int*)(xptr))[threadIdx.x]; \
            if (((wrd >> 7) & 0xFF) >= 0xE0) atomicAdd(&s_cnt, 1);      \
        }                                                               \
        __syncthreads();                                                \
        result = (s_cnt > 8);                                           \
    }

// ---------------- Kernel A: per (head, graph) attention, O (fp32) written into d_out ----------------
template<bool F32>
__device__ void attn_body(const void* x, const void* w_in, const void* b_in,
                          const void* aggrs, float* O) {
    const int h = blockIdx.x;  // 0..7
    const int g = blockIdx.y;  // 0..63
    const int tid = threadIdx.x;
    const int w = tid >> 6;    // wave 0..3
    const int lane = tid & 63;
    const int l15 = lane & 15;
    const int l4 = lane >> 4;  // 0..3

    __shared__ __align__(16) unsigned short Q_lds[32][72];
    __shared__ __align__(16) unsigned short K_lds[128][72];
    __shared__ __align__(16) unsigned short Vt_lds[64][136];
    __shared__ __align__(16) float S_lds[32][132];
    __shared__ __align__(16) unsigned short P_lds[32][136];

    const long xg = (long)g * 128 * 512;
    const long WqO = (long)(h * 64) * 512;
    const long WkO = (long)(512 + h * 64) * 512;
    const long WvO = (long)(1024 + h * 64) * 512;

    // ---- Phase 0: Q_h = aggrs @ Wq_h^T + bq  (32x64); wave w owns col tile d0=w*16 ----
    {
        const int d0 = w * 16;
        const float bq = loadf<F32>(b_in, h * 64 + d0 + l15);
        for (int rt = 0; rt < 2; ++rt) {
            f32x4 acc = {0.f, 0.f, 0.f, 0.f};
#pragma unroll
            for (int kk = 0; kk < 16; ++kk) {
                short8 a = load8<F32>(aggrs, (long)(rt * 16 + l15) * 512 + l4 * 8 + kk * 32);
                short8 b = load8<F32>(w_in, WqO + (long)(d0 + l15) * 512 + l4 * 8 + kk * 32);
                acc = __builtin_amdgcn_mfma_f32_16x16x32_bf16(a, b, acc, 0, 0, 0);
            }
#pragma unroll
            for (int r = 0; r < 4; ++r)
                Q_lds[rt * 16 + l4 * 4 + r][d0 + l15] = f2bf(acc[r] + bq);
        }
    }
    // (no sync needed: Q_lds first read after the phase-1 __syncthreads)

    // ---- Phase 1: K_h = x[g] @ Wk_h^T, V_h = x[g] @ Wv_h^T ----
    for (int rt = 0; rt < 2; ++rt) {
        const int n0 = w * 32 + rt * 16;
        short8 a[16];
#pragma unroll
        for (int kk = 0; kk < 16; ++kk)
            a[kk] = load8<F32>(x, xg + (long)(n0 + l15) * 512 + l4 * 8 + kk * 32);
        for (int ct = 0; ct < 4; ++ct) {
            const int d0 = ct * 16;
            f32x4 accK = {0.f, 0.f, 0.f, 0.f};
            f32x4 accV = {0.f, 0.f, 0.f, 0.f};
#pragma unroll
            for (int kk = 0; kk < 16; ++kk) {
                short8 bk = load8<F32>(w_in, WkO + (long)(d0 + l15) * 512 + l4 * 8 + kk * 32);
                short8 bv = load8<F32>(w_in, WvO + (long)(d0 + l15) * 512 + l4 * 8 + kk * 32);
                accK = __builtin_amdgcn_mfma_f32_16x16x32_bf16(a[kk], bk, accK, 0, 0, 0);
                accV = __builtin_amdgcn_mfma_f32_16x16x32_bf16(a[kk], bv, accV, 0, 0, 0);
            }
            const float biasK = loadf<F32>(b_in, 512 + h * 64 + d0 + l15);
            const float biasV = loadf<F32>(b_in, 1024 + h * 64 + d0 + l15);
#pragma unroll
            for (int r = 0; r < 4; ++r) {
                const int row = n0 + l4 * 4 + r;  // node
                const int col = d0 + l15;         // head dim
                K_lds[row][col] = f2bf(accK[r] + biasK);
                Vt_lds[col][row] = f2bf(accV[r] + biasV);
            }
        }
    }
    __syncthreads();

    // ---- Phase 2: S = (Q_h @ K_h^T) * 0.125 ----
    for (int lt = 0; lt < 2; ++lt) {
        const int l0 = lt * 16;
        short8 qa[2];
        qa[0] = *(const short8*)(&Q_lds[l0 + l15][l4 * 8]);
        qa[1] = *(const short8*)(&Q_lds[l0 + l15][32 + l4 * 8]);
        for (int ct = 0; ct < 2; ++ct) {
            const int n0 = w * 32 + ct * 16;
            f32x4 acc = {0.f, 0.f, 0.f, 0.f};
#pragma unroll
            for (int kk = 0; kk < 2; ++kk) {
                short8 b = *(const short8*)(&K_lds[n0 + l15][kk * 32 + l4 * 8]);
                acc = __builtin_amdgcn_mfma_f32_16x16x32_bf16(qa[kk], b, acc, 0, 0, 0);
            }
#pragma unroll
            for (int r = 0; r < 4; ++r)
                S_lds[l0 + l4 * 4 + r][n0 + l15] = acc[r] * 0.125f;
        }
    }
    __syncthreads();

    // ---- Phase 3: row softmax over 128 nodes ----
    {
        const int row = tid >> 3;
        const int j = tid & 7;
        float vals[16];
        float m = -1e30f;
#pragma unroll
        for (int c = 0; c < 16; ++c) {
            vals[c] = S_lds[row][j + c * 8];
            m = fmaxf(m, vals[c]);
        }
#pragma unroll
        for (int s = 1; s < 8; s <<= 1) m = fmaxf(m, __shfl_xor(m, s));
        float sum = 0.f;
#pragma unroll
        for (int c = 0; c < 16; ++c) {
            vals[c] = __expf(vals[c] - m);
            sum += vals[c];
        }
#pragma unroll
        for (int s = 1; s < 8; s <<= 1) sum += __shfl_xor(sum, s);
        const float inv = 1.0f / sum;
#pragma unroll
        for (int c = 0; c < 16; ++c)
            P_lds[row][j + c * 8] = f2bf(vals[c] * inv);
    }
    __syncthreads();

    // ---- Phase 4: O_h = P @ V_h  (write fp32) ----
    for (int lt = 0; lt < 2; ++lt) {
        const int l0 = lt * 16;
        const int d0 = w * 16;
        f32x4 acc = {0.f, 0.f, 0.f, 0.f};
#pragma unroll
        for (int kk = 0; kk < 4; ++kk) {
            short8 a = *(const short8*)(&P_lds[l0 + l15][kk * 32 + l4 * 8]);
            short8 b = *(const short8*)(&Vt_lds[d0 + l15][kk * 32 + l4 * 8]);
            acc = __builtin_amdgcn_mfma_f32_16x16x32_bf16(a, b, acc, 0, 0, 0);
        }
#pragma unroll
        for (int r = 0; r < 4; ++r) {
            const int l = l0 + l4 * 4 + r;
            O[(long)(g * 32 + l) * 512 + h * 64 + d0 + l15] = acc[r];
        }
    }
}

__global__ __launch_bounds__(256) void attn_kernel(const void* x, const void* w_in,
                                                   const void* b_in, const void* aggrs,
                                                   float* O) {
    bool isf32;
    DETECT_F32(x, isf32);
    if (isf32) attn_body<true>(x, w_in, b_in, aggrs, O);
    else       attn_body<false>(x, w_in, b_in, aggrs, O);
}

// ---------------- Kernel B: in-place out = O @ Wo^T + bo on d_out (fp32) ----------------
// Each block owns 16 rows: stages them to LDS (as bf16 fragments), syncs, then
// overwrites them. Row r of out depends ONLY on row r of O -> in-place is safe.
template<bool F32>
__device__ void outproj_body(float* Out, const void* Wo, const void* bo) {
    const int by = blockIdx.x;  // 0..127
    const int tid = threadIdx.x;
    const int w = tid >> 6;
    const int lane = tid & 63;
    const int l15 = lane & 15;
    const int l4 = lane >> 4;

    __shared__ __align__(16) unsigned short O_lds[16][520];

#pragma unroll
    for (int i = 0; i < 4; ++i) {
        int c2 = tid + i * 256;       // 0..1023 = 16 rows x 64 chunks of 8
        int row = c2 >> 6;
        int col = (c2 & 63) * 8;
        const float* src = Out + (long)(by * 16 + row) * 512 + col;
        f32x4 a = *(const f32x4*)src;
        f32x4 b = *(const f32x4*)(src + 4);
        short8 v;
#pragma unroll
        for (int j = 0; j < 4; ++j) { v[j] = (short)f2bf(a[j]); v[4 + j] = (short)f2bf(b[j]); }
        *(short8*)(&O_lds[row][col]) = v;
    }
    __syncthreads();

    short8 a[16];
#pragma unroll
    for (int kk = 0; kk < 16; ++kk)
        a[kk] = *(const short8*)(&O_lds[l15][kk * 32 + l4 * 8]);

    const int cbase = w * 128;
    for (int ct = 0; ct < 8; ++ct) {
        const int col0 = cbase + ct * 16;
        f32x4 acc = {0.f, 0.f, 0.f, 0.f};
#pragma unroll
        for (int kk = 0; kk < 16; ++kk) {
            short8 b = load8<F32>(Wo, (long)(col0 + l15) * 512 + l4 * 8 + kk * 32);
            acc = __builtin_amdgcn_mfma_f32_16x16x32_bf16(a[kk], b, acc, 0, 0, 0);
        }
        const float bias = loadf<F32>(bo, col0 + l15);
#pragma unroll
        for (int r = 0; r < 4; ++r)
            Out[(long)(by * 16 + l4 * 4 + r) * 512 + col0 + l15] = acc[r] + bias;
    }
}

__global__ __launch_bounds__(256) void outproj_kernel(float* Out, const void* Wo,
                                                      const void* bo, const void* xdet) {
    bool isf32;
    DETECT_F32(xdet, isf32);
    if (isf32) outproj_body<true>(Out, Wo, bo);
    else       outproj_body<false>(Out, Wo, bo);
}

extern "C" void kernel_launch(void* const* d_in, const int* in_sizes, int n_in,
                              void* d_out, int out_size, void* d_ws, size_t ws_size,
                              hipStream_t stream) {
    // Size-based input dispatch — all 7 element counts are distinct, so this is
    // robust to ANY input ordering (no-op if already dict order).
    const int want[7] = {64 * 128 * 512,  // x
                         64 * 128,        // batch (int32, unused)
                         32 * 512,        // aggrs
                         1536 * 512,      // in_proj_w
                         1536,            // in_proj_b
                         512 * 512,       // out_proj_w
                         512};            // out_proj_b
    const void* p[7] = {0, 0, 0, 0, 0, 0, 0};
    for (int i = 0; i < n_in && i < 16; ++i)
        for (int j = 0; j < 7; ++j)
            if (in_sizes[i] == want[j] && p[j] == 0) { p[j] = d_in[i]; break; }

    const void* x          = p[0];
    const void* aggrs      = p[2];
    const void* in_proj_w  = p[3];
    const void* in_proj_b  = p[4];
    const void* out_proj_w = p[5];
    const void* out_proj_b = p[6];
    float* out = (float*)d_out;  // (2048,512) fp32; also holds the O intermediate

    attn_kernel<<<dim3(8, 64), dim3(256), 0, stream>>>(x, in_proj_w, in_proj_b, aggrs, out);
    outproj_kernel<<<dim3(128), dim3(256), 0, stream>>>(out, out_proj_w, out_proj_b, x);
}

// Round 6
// 126.943 us; speedup vs baseline: 2.4069x; 2.4069x over previous
//
#include <hip/hip_runtime.h>

typedef __attribute__((ext_vector_type(8))) short short8;
typedef __attribute__((ext_vector_type(4))) float f32x4;

__device__ inline float bf2f(unsigned short u) {
    return __uint_as_float(((unsigned int)u) << 16);
}
__device__ inline unsigned short f2bf(float f) {
    unsigned int x = __float_as_uint(f);
    return (unsigned short)((x + 0x7fffu + ((x >> 16) & 1u)) >> 16);
}

template<bool F32>
__device__ inline short8 load8(const void* p, long i) {  // i % 8 == 0 at all call sites
    short8 r;
    if (F32) {
        const float* fp = (const float*)p + i;
        f32x4 a = *(const f32x4*)fp;
        f32x4 b = *(const f32x4*)(fp + 4);
#pragma unroll
        for (int j = 0; j < 4; ++j) { r[j] = (short)f2bf(a[j]); r[4 + j] = (short)f2bf(b[j]); }
    } else {
        r = *(const short8*)((const unsigned short*)p + i);
    }
    return r;
}

// ---------------- Kernel 0: fp32 -> bf16 pre-convert into ws ----------------
// Segments (in units of 8 elements): in_proj_w 98304 | out_proj_w 32768 | aggrs 2048 | x 524288
__global__ __launch_bounds__(256) void convert_kernel(
    const float* __restrict__ inW, const float* __restrict__ outW,
    const float* __restrict__ aggrs, const float* __restrict__ x,
    unsigned short* __restrict__ ws) {
    long u = (long)blockIdx.x * 256 + threadIdx.x;
    const float* src;
    unsigned short* dst;
    long base;
    if (u < 98304)       { src = inW;   dst = ws;           base = u; }
    else if (u < 131072) { src = outW;  dst = ws + 786432;  base = u - 98304; }
    else if (u < 133120) { src = aggrs; dst = ws + 1048576; base = u - 131072; }
    else if (u < 657408) { src = x;     dst = ws + 1064960; base = u - 133120; }
    else return;
    long i = base * 8;
    f32x4 a = *(const f32x4*)(src + i);
    f32x4 b = *(const f32x4*)(src + i + 4);
    short8 v;
#pragma unroll
    for (int j = 0; j < 4; ++j) { v[j] = (short)f2bf(a[j]); v[4 + j] = (short)f2bf(b[j]); }
    *(short8*)(dst + i) = v;
}

// ---------------- per (head, graph) attention, O (fp32) written into d_out ----------------
// F32: whether x/w/aggrs are fp32 (fallback) or pre-converted bf16 (fast). Biases always fp32.
template<bool F32>
__device__ void attn_body(const void* x, const void* w_in, const float* b_in,
                          const void* aggrs, float* O) {
    const int h = blockIdx.x;  // 0..7
    const int g = blockIdx.y;  // 0..63
    const int tid = threadIdx.x;
    const int w = tid >> 6;    // wave 0..3
    const int lane = tid & 63;
    const int l15 = lane & 15;
    const int l4 = lane >> 4;  // 0..3

    __shared__ __align__(16) unsigned short Q_lds[32][72];
    __shared__ __align__(16) unsigned short K_lds[128][72];
    __shared__ __align__(16) unsigned short Vt_lds[64][136];
    __shared__ __align__(16) float S_lds[32][132];
    __shared__ __align__(16) unsigned short P_lds[32][136];

    const long xg = (long)g * 128 * 512;
    const long WqO = (long)(h * 64) * 512;
    const long WkO = (long)(512 + h * 64) * 512;
    const long WvO = (long)(1024 + h * 64) * 512;

    // ---- Phase 0: Q_h = aggrs @ Wq_h^T + bq  (32x64); wave w owns col tile d0=w*16 ----
    {
        const int d0 = w * 16;
        const float bq = b_in[h * 64 + d0 + l15];
        for (int rt = 0; rt < 2; ++rt) {
            f32x4 acc = {0.f, 0.f, 0.f, 0.f};
#pragma unroll
            for (int kk = 0; kk < 16; ++kk) {
                short8 a = load8<F32>(aggrs, (long)(rt * 16 + l15) * 512 + l4 * 8 + kk * 32);
                short8 b = load8<F32>(w_in, WqO + (long)(d0 + l15) * 512 + l4 * 8 + kk * 32);
                acc = __builtin_amdgcn_mfma_f32_16x16x32_bf16(a, b, acc, 0, 0, 0);
            }
#pragma unroll
            for (int r = 0; r < 4; ++r)
                Q_lds[rt * 16 + l4 * 4 + r][d0 + l15] = f2bf(acc[r] + bq);
        }
    }
    // (no sync needed: Q_lds first read after the phase-1 __syncthreads)

    // ---- Phase 1: K_h = x[g] @ Wk_h^T, V_h = x[g] @ Wv_h^T ----
    for (int rt = 0; rt < 2; ++rt) {
        const int n0 = w * 32 + rt * 16;
        short8 a[16];
#pragma unroll
        for (int kk = 0; kk < 16; ++kk)
            a[kk] = load8<F32>(x, xg + (long)(n0 + l15) * 512 + l4 * 8 + kk * 32);
        for (int ct = 0; ct < 4; ++ct) {
            const int d0 = ct * 16;
            f32x4 accK = {0.f, 0.f, 0.f, 0.f};
            f32x4 accV = {0.f, 0.f, 0.f, 0.f};
#pragma unroll
            for (int kk = 0; kk < 16; ++kk) {
                short8 bk = load8<F32>(w_in, WkO + (long)(d0 + l15) * 512 + l4 * 8 + kk * 32);
                short8 bv = load8<F32>(w_in, WvO + (long)(d0 + l15) * 512 + l4 * 8 + kk * 32);
                accK = __builtin_amdgcn_mfma_f32_16x16x32_bf16(a[kk], bk, accK, 0, 0, 0);
                accV = __builtin_amdgcn_mfma_f32_16x16x32_bf16(a[kk], bv, accV, 0, 0, 0);
            }
            const float biasK = b_in[512 + h * 64 + d0 + l15];
            const float biasV = b_in[1024 + h * 64 + d0 + l15];
#pragma unroll
            for (int r = 0; r < 4; ++r) {
                const int row = n0 + l4 * 4 + r;  // node
                const int col = d0 + l15;         // head dim
                K_lds[row][col] = f2bf(accK[r] + biasK);
                Vt_lds[col][row] = f2bf(accV[r] + biasV);
            }
        }
    }
    __syncthreads();

    // ---- Phase 2: S = (Q_h @ K_h^T) * 0.125 ----
    for (int lt = 0; lt < 2; ++lt) {
        const int l0 = lt * 16;
        short8 qa[2];
        qa[0] = *(const short8*)(&Q_lds[l0 + l15][l4 * 8]);
        qa[1] = *(const short8*)(&Q_lds[l0 + l15][32 + l4 * 8]);
        for (int ct = 0; ct < 2; ++ct) {
            const int n0 = w * 32 + ct * 16;
            f32x4 acc = {0.f, 0.f, 0.f, 0.f};
#pragma unroll
            for (int kk = 0; kk < 2; ++kk) {
                short8 b = *(const short8*)(&K_lds[n0 + l15][kk * 32 + l4 * 8]);
                acc = __builtin_amdgcn_mfma_f32_16x16x32_bf16(qa[kk], b, acc, 0, 0, 0);
            }
#pragma unroll
            for (int r = 0; r < 4; ++r)
                S_lds[l0 + l4 * 4 + r][n0 + l15] = acc[r] * 0.125f;
        }
    }
    __syncthreads();

    // ---- Phase 3: row softmax over 128 nodes ----
    {
        const int row = tid >> 3;
        const int j = tid & 7;
        float vals[16];
        float m = -1e30f;
#pragma unroll
        for (int c = 0; c < 16; ++c) {
            vals[c] = S_lds[row][j + c * 8];
            m = fmaxf(m, vals[c]);
        }
#pragma unroll
        for (int s = 1; s < 8; s <<= 1) m = fmaxf(m, __shfl_xor(m, s));
        float sum = 0.f;
#pragma unroll
        for (int c = 0; c < 16; ++c) {
            vals[c] = __expf(vals[c] - m);
            sum += vals[c];
        }
#pragma unroll
        for (int s = 1; s < 8; s <<= 1) sum += __shfl_xor(sum, s);
        const float inv = 1.0f / sum;
#pragma unroll
        for (int c = 0; c < 16; ++c)
            P_lds[row][j + c * 8] = f2bf(vals[c] * inv);
    }
    __syncthreads();

    // ---- Phase 4: O_h = P @ V_h  (write fp32) ----
    for (int lt = 0; lt < 2; ++lt) {
        const int l0 = lt * 16;
        const int d0 = w * 16;
        f32x4 acc = {0.f, 0.f, 0.f, 0.f};
#pragma unroll
        for (int kk = 0; kk < 4; ++kk) {
            short8 a = *(const short8*)(&P_lds[l0 + l15][kk * 32 + l4 * 8]);
            short8 b = *(const short8*)(&Vt_lds[d0 + l15][kk * 32 + l4 * 8]);
            acc = __builtin_amdgcn_mfma_f32_16x16x32_bf16(a, b, acc, 0, 0, 0);
        }
#pragma unroll
        for (int r = 0; r < 4; ++r) {
            const int l = l0 + l4 * 4 + r;
            O[(long)(g * 32 + l) * 512 + h * 64 + d0 + l15] = acc[r];
        }
    }
}

// Separate __global__ wrappers so each kernel carries exactly ONE instantiation's LDS.
__global__ __launch_bounds__(256, 2) void attn_fast(const unsigned short* xb,
                                                    const unsigned short* wb,
                                                    const float* b_in,
                                                    const unsigned short* agb, float* O) {
    attn_body<false>(xb, wb, b_in, agb, O);
}
__global__ __launch_bounds__(256) void attn_f32(const float* x, const float* w_in,
                                                const float* b_in, const float* aggrs,
                                                float* O) {
    attn_body<true>(x, w_in, b_in, aggrs, O);
}

// ---------------- in-place out = O @ Wo^T + bo on d_out (fp32) ----------------
// Each block owns 16 rows: stages them to LDS (bf16), syncs, overwrites them.
template<bool F32>
__device__ void outproj_body(float* Out, const void* Wo, const float* bo) {
    const int by = blockIdx.x;  // 0..127
    const int tid = threadIdx.x;
    const int w = tid >> 6;
    const int lane = tid & 63;
    const int l15 = lane & 15;
    const int l4 = lane >> 4;

    __shared__ __align__(16) unsigned short O_lds[16][520];

#pragma unroll
    for (int i = 0; i < 4; ++i) {
        int c2 = tid + i * 256;       // 0..1023 = 16 rows x 64 chunks of 8
        int row = c2 >> 6;
        int col = (c2 & 63) * 8;
        const float* src = Out + (long)(by * 16 + row) * 512 + col;
        f32x4 a = *(const f32x4*)src;
        f32x4 b = *(const f32x4*)(src + 4);
        short8 v;
#pragma unroll
        for (int j = 0; j < 4; ++j) { v[j] = (short)f2bf(a[j]); v[4 + j] = (short)f2bf(b[j]); }
        *(short8*)(&O_lds[row][col]) = v;
    }
    __syncthreads();

    short8 a[16];
#pragma unroll
    for (int kk = 0; kk < 16; ++kk)
        a[kk] = *(const short8*)(&O_lds[l15][kk * 32 + l4 * 8]);

    const int cbase = w * 128;
    for (int ct = 0; ct < 8; ++ct) {
        const int col0 = cbase + ct * 16;
        f32x4 acc = {0.f, 0.f, 0.f, 0.f};
#pragma unroll
        for (int kk = 0; kk < 16; ++kk) {
            short8 b = load8<F32>(Wo, (long)(col0 + l15) * 512 + l4 * 8 + kk * 32);
            acc = __builtin_amdgcn_mfma_f32_16x16x32_bf16(a[kk], b, acc, 0, 0, 0);
        }
        const float bias = bo[col0 + l15];
#pragma unroll
        for (int r = 0; r < 4; ++r)
            Out[(long)(by * 16 + l4 * 4 + r) * 512 + col0 + l15] = acc[r] + bias;
    }
}

__global__ __launch_bounds__(256, 2) void outproj_fast(float* Out, const unsigned short* Wob,
                                                       const float* bo) {
    outproj_body<false>(Out, Wob, bo);
}
__global__ __launch_bounds__(256) void outproj_f32(float* Out, const float* Wo,
                                                   const float* bo) {
    outproj_body<true>(Out, Wo, bo);
}

extern "C" void kernel_launch(void* const* d_in, const int* in_sizes, int n_in,
                              void* d_out, int out_size, void* d_ws, size_t ws_size,
                              hipStream_t stream) {
    // Size-based input dispatch — all 7 element counts distinct -> robust to any ordering.
    const int want[7] = {64 * 128 * 512,  // x
                         64 * 128,        // batch (int32, unused)
                         32 * 512,        // aggrs
                         1536 * 512,      // in_proj_w
                         1536,            // in_proj_b
                         512 * 512,       // out_proj_w
                         512};            // out_proj_b
    const void* p[7] = {0, 0, 0, 0, 0, 0, 0};
    for (int i = 0; i < n_in && i < 16; ++i)
        for (int j = 0; j < 7; ++j)
            if (in_sizes[i] == want[j] && p[j] == 0) { p[j] = d_in[i]; break; }

    const float* x     = (const float*)p[0];
    const float* aggrs = (const float*)p[2];
    const float* w_in  = (const float*)p[3];
    const float* b_in  = (const float*)p[4];
    const float* Wo    = (const float*)p[5];
    const float* bo    = (const float*)p[6];
    float* out = (float*)d_out;  // (2048,512) fp32; also holds the O intermediate

    const size_t need = (size_t)(786432 + 262144 + 16384 + 4194304) * 2;  // 10.5 MB bf16
    if (ws_size >= need) {
        unsigned short* ws = (unsigned short*)d_ws;
        const unsigned short* wb  = ws;             // in_proj_w bf16
        const unsigned short* wob = ws + 786432;    // out_proj_w bf16
        const unsigned short* agb = ws + 1048576;   // aggrs bf16
        const unsigned short* xb  = ws + 1064960;   // x bf16
        convert_kernel<<<dim3(2568), dim3(256), 0, stream>>>(w_in, Wo, aggrs, x, ws);
        attn_fast<<<dim3(8, 64), dim3(256), 0, stream>>>(xb, wb, b_in, agb, out);
        outproj_fast<<<dim3(128), dim3(256), 0, stream>>>(out, wob, bo);
    } else {
        attn_f32<<<dim3(8, 64), dim3(256), 0, stream>>>(x, w_in, b_in, aggrs, out);
        outproj_f32<<<dim3(128), dim3(256), 0, stream>>>(out, Wo, bo);
    }
}

// Round 7
// 74.100 us; speedup vs baseline: 4.1234x; 1.7131x over previous
//
#include <hip/hip_runtime.h>

typedef __attribute__((ext_vector_type(8))) short short8;
typedef __attribute__((ext_vector_type(4))) float f32x4;

__device__ inline float bf2f(unsigned short u) {
    return __uint_as_float(((unsigned int)u) << 16);
}
__device__ inline unsigned short f2bf(float f) {
    unsigned int x = __float_as_uint(f);
    return (unsigned short)((x + 0x7fffu + ((x >> 16) & 1u)) >> 16);
}

template<bool F32>
__device__ inline short8 load8(const void* p, long i) {  // i % 8 == 0 at all call sites
    short8 r;
    if (F32) {
        const float* fp = (const float*)p + i;
        f32x4 a = *(const f32x4*)fp;
        f32x4 b = *(const f32x4*)(fp + 4);
#pragma unroll
        for (int j = 0; j < 4; ++j) { r[j] = (short)f2bf(a[j]); r[4 + j] = (short)f2bf(b[j]); }
    } else {
        r = *(const short8*)((const unsigned short*)p + i);
    }
    return r;
}

// ---------------- fp32 -> bf16 pre-convert into ws ----------------
// Segments (units of 8 elems): in_proj_w 98304 | out_proj_w 32768 | aggrs 2048 | x 524288
__global__ __launch_bounds__(256) void convert_kernel(
    const float* __restrict__ inW, const float* __restrict__ outW,
    const float* __restrict__ aggrs, const float* __restrict__ x,
    unsigned short* __restrict__ ws) {
    long u = (long)blockIdx.x * 256 + threadIdx.x;
    const float* src;
    unsigned short* dst;
    long base;
    if (u < 98304)       { src = inW;   dst = ws;           base = u; }
    else if (u < 131072) { src = outW;  dst = ws + 786432;  base = u - 98304; }
    else if (u < 133120) { src = aggrs; dst = ws + 1048576; base = u - 131072; }
    else if (u < 657408) { src = x;     dst = ws + 1064960; base = u - 133120; }
    else return;
    long i = base * 8;
    f32x4 a = *(const f32x4*)(src + i);
    f32x4 b = *(const f32x4*)(src + i + 4);
    short8 v;
#pragma unroll
    for (int j = 0; j < 4; ++j) { v[j] = (short)f2bf(a[j]); v[4 + j] = (short)f2bf(b[j]); }
    *(short8*)(dst + i) = v;
}

// ---------------- Qs = aggrs @ Wq^T + bq  (32x512 bf16), grid 8 ----------------
__global__ __launch_bounds__(256) void qproj2_kernel(
    const unsigned short* __restrict__ agb, const unsigned short* __restrict__ wb,
    const float* __restrict__ b_in, unsigned short* __restrict__ Qs) {
    const int tid = threadIdx.x;
    const int w = tid >> 6, lane = tid & 63, l15 = lane & 15, l4 = lane >> 4;
    const int col0 = blockIdx.x * 64 + w * 16;
    const float bq = b_in[col0 + l15];
    for (int rt = 0; rt < 2; ++rt) {
        f32x4 acc = {0.f, 0.f, 0.f, 0.f};
#pragma unroll
        for (int kk = 0; kk < 16; ++kk) {
            short8 a = *(const short8*)(agb + (long)(rt * 16 + l15) * 512 + kk * 32 + l4 * 8);
            short8 b = *(const short8*)(wb + (long)(col0 + l15) * 512 + kk * 32 + l4 * 8);
            acc = __builtin_amdgcn_mfma_f32_16x16x32_bf16(a, b, acc, 0, 0, 0);
        }
#pragma unroll
        for (int r = 0; r < 4; ++r)
            Qs[(long)(rt * 16 + l4 * 4 + r) * 512 + col0 + l15] = f2bf(acc[r] + bq);
    }
}

// ---------------- KV = X @ [Wk;Wv]^T + b  (8192x1024 bf16), grid 256 ----------------
// Per block: 64 rows x 512 cols (col half ch). A-fragments live in registers (read
// once); B chunks staged through a 64KB XOR-swizzled LDS tile (kills the stride-1KB
// bank conflict on ds_read_b128).
__global__ __launch_bounds__(256, 2) void kvgemm_kernel(
    const unsigned short* __restrict__ xb,   // (8192,512)
    const unsigned short* __restrict__ wb,   // (1536,512)
    const float* __restrict__ b_in,          // (1536) fp32
    unsigned short* __restrict__ KV)         // (8192,1024)
{
    const int rb = blockIdx.x >> 1;   // row block (64 rows)
    const int ch = blockIdx.x & 1;    // col half (512 cols)
    const int tid = threadIdx.x;
    const int w = tid >> 6, lane = tid & 63, l15 = lane & 15, l4 = lane >> 4;

    __shared__ __align__(16) unsigned short B_lds[64][512];  // exactly 64 KB, swizzled

    const int row0 = rb * 64;
    short8 a[16];  // wave w's 16 rows x K=512
#pragma unroll
    for (int kk = 0; kk < 16; ++kk)
        a[kk] = *(const short8*)(xb + (long)(row0 + w * 16 + l15) * 512 + kk * 32 + l4 * 8);

    const int wrow0 = 512 + ch * 512;
    for (int cb = 0; cb < 8; ++cb) {
        if (cb) __syncthreads();
#pragma unroll
        for (int j = 0; j < 16; ++j) {
            int c = tid + j * 256;
            int row = c >> 6;     // 0..63
            int col8 = c & 63;    // 16B unit
            *(short8*)(&B_lds[row][(col8 ^ (row & 7)) * 8]) =
                *(const short8*)(wb + (long)(wrow0 + cb * 64 + row) * 512 + col8 * 8);
        }
        __syncthreads();
#pragma unroll
        for (int ct = 0; ct < 4; ++ct) {
            const int brow = ct * 16 + l15;
            f32x4 acc = {0.f, 0.f, 0.f, 0.f};
#pragma unroll
            for (int kk = 0; kk < 16; ++kk) {
                short8 b = *(const short8*)(&B_lds[brow][((kk * 4 + l4) ^ (l15 & 7)) * 8]);
                acc = __builtin_amdgcn_mfma_f32_16x16x32_bf16(a[kk], b, acc, 0, 0, 0);
            }
            const int col = ch * 512 + cb * 64 + ct * 16 + l15;
            const float bias = b_in[512 + col];
#pragma unroll
            for (int r = 0; r < 4; ++r)
                KV[(long)(row0 + w * 16 + l4 * 4 + r) * 1024 + col] = f2bf(acc[r] + bias);
        }
    }
}

// ---------------- attention per (g,h): reads precomputed KV + Qs ----------------
__global__ __launch_bounds__(256, 2) void attn2_kernel(
    const unsigned short* __restrict__ KV,  // (8192,1024)
    const unsigned short* __restrict__ Qs,  // (32,512)
    unsigned short* __restrict__ Oh)        // (8,2048,64)
{
    const int h = blockIdx.x;  // 0..7
    const int g = blockIdx.y;  // 0..63
    const int tid = threadIdx.x;
    const int w = tid >> 6, lane = tid & 63, l15 = lane & 15, l4 = lane >> 4;

    __shared__ __align__(16) unsigned short K_lds[128][72];
    __shared__ __align__(16) unsigned short Vt_lds[64][136];
    __shared__ __align__(16) float S_lds[32][132];
    __shared__ __align__(16) unsigned short P_lds[32][136];

    // stage K_h (128x64) and V_h^T (64x128)
#pragma unroll
    for (int j = 0; j < 4; ++j) {
        int c = tid + j * 256;       // 0..1023
        int row = c >> 3;            // 0..127
        int col = (c & 7) * 8;       // 0..56
        *(short8*)(&K_lds[row][col]) =
            *(const short8*)(KV + (long)(g * 128 + row) * 1024 + h * 64 + col);
    }
#pragma unroll
    for (int j = 0; j < 4; ++j) {
        int c = tid + j * 256;
        int row = c >> 3;
        int col = (c & 7) * 8;
        short8 v = *(const short8*)(KV + (long)(g * 128 + row) * 1024 + 512 + h * 64 + col);
#pragma unroll
        for (int e = 0; e < 8; ++e)
            Vt_lds[col + e][row] = (unsigned short)v[e];
    }
    __syncthreads();

    // S = (Q_h @ K_h^T) * 0.125
    for (int lt = 0; lt < 2; ++lt) {
        const int l0 = lt * 16;
        short8 qa[2];
        qa[0] = *(const short8*)(Qs + (long)(l0 + l15) * 512 + h * 64 + l4 * 8);
        qa[1] = *(const short8*)(Qs + (long)(l0 + l15) * 512 + h * 64 + 32 + l4 * 8);
        for (int ct = 0; ct < 2; ++ct) {
            const int n0 = w * 32 + ct * 16;
            f32x4 acc = {0.f, 0.f, 0.f, 0.f};
#pragma unroll
            for (int kk = 0; kk < 2; ++kk) {
                short8 b = *(const short8*)(&K_lds[n0 + l15][kk * 32 + l4 * 8]);
                acc = __builtin_amdgcn_mfma_f32_16x16x32_bf16(qa[kk], b, acc, 0, 0, 0);
            }
#pragma unroll
            for (int r = 0; r < 4; ++r)
                S_lds[l0 + l4 * 4 + r][n0 + l15] = acc[r] * 0.125f;
        }
    }
    __syncthreads();

    // row softmax over 128 nodes
    {
        const int row = tid >> 3;
        const int j = tid & 7;
        float vals[16];
        float m = -1e30f;
#pragma unroll
        for (int c = 0; c < 16; ++c) {
            vals[c] = S_lds[row][j + c * 8];
            m = fmaxf(m, vals[c]);
        }
#pragma unroll
        for (int s = 1; s < 8; s <<= 1) m = fmaxf(m, __shfl_xor(m, s));
        float sum = 0.f;
#pragma unroll
        for (int c = 0; c < 16; ++c) {
            vals[c] = __expf(vals[c] - m);
            sum += vals[c];
        }
#pragma unroll
        for (int s = 1; s < 8; s <<= 1) sum += __shfl_xor(sum, s);
        const float inv = 1.0f / sum;
#pragma unroll
        for (int c = 0; c < 16; ++c)
            P_lds[row][j + c * 8] = f2bf(vals[c] * inv);
    }
    __syncthreads();

    // O_h = P @ V_h -> Oh[h][g*32+l][d] (bf16, head-contiguous)
    for (int lt = 0; lt < 2; ++lt) {
        const int l0 = lt * 16;
        const int d0 = w * 16;
        f32x4 acc = {0.f, 0.f, 0.f, 0.f};
#pragma unroll
        for (int kk = 0; kk < 4; ++kk) {
            short8 a = *(const short8*)(&P_lds[l0 + l15][kk * 32 + l4 * 8]);
            short8 b = *(const short8*)(&Vt_lds[d0 + l15][kk * 32 + l4 * 8]);
            acc = __builtin_amdgcn_mfma_f32_16x16x32_bf16(a, b, acc, 0, 0, 0);
        }
#pragma unroll
        for (int r = 0; r < 4; ++r) {
            const int l = l0 + l4 * 4 + r;
            Oh[(long)h * 131072 + (long)(g * 32 + l) * 64 + d0 + l15] = f2bf(acc[r]);
        }
    }
}

// ---------------- out = Oh-gathered @ Wo^T + bo  (fp32 to d_out), grid 128 ----------------
__global__ __launch_bounds__(256, 2) void outproj2_kernel(
    const unsigned short* __restrict__ Oh, const unsigned short* __restrict__ wob,
    const float* __restrict__ bo, float* __restrict__ out)
{
    const int by = blockIdx.x;  // 0..127 (16 rows each)
    const int tid = threadIdx.x;
    const int w = tid >> 6, lane = tid & 63, l15 = lane & 15, l4 = lane >> 4;

    __shared__ __align__(16) unsigned short O_lds[16][520];

#pragma unroll
    for (int i = 0; i < 4; ++i) {
        int c2 = tid + i * 256;       // 16 rows x 64 chunks of 8
        int row = c2 >> 6;
        int c = c2 & 63;
        int hh = c >> 3;
        int d = (c & 7) * 8;
        *(short8*)(&O_lds[row][c * 8]) =
            *(const short8*)(Oh + (long)hh * 131072 + (long)(by * 16 + row) * 64 + d);
    }
    __syncthreads();

    short8 a[16];
#pragma unroll
    for (int kk = 0; kk < 16; ++kk)
        a[kk] = *(const short8*)(&O_lds[l15][kk * 32 + l4 * 8]);

    const int cbase = w * 128;
    for (int ct = 0; ct < 8; ++ct) {
        const int col0 = cbase + ct * 16;
        f32x4 acc = {0.f, 0.f, 0.f, 0.f};
#pragma unroll
        for (int kk = 0; kk < 16; ++kk) {
            short8 b = *(const short8*)(wob + (long)(col0 + l15) * 512 + kk * 32 + l4 * 8);
            acc = __builtin_amdgcn_mfma_f32_16x16x32_bf16(a[kk], b, acc, 0, 0, 0);
        }
        const float bias = bo[col0 + l15];
#pragma unroll
        for (int r = 0; r < 4; ++r)
            out[(long)(by * 16 + l4 * 4 + r) * 512 + col0 + l15] = acc[r] + bias;
    }
}

// ================= round-6 fallback path (ws >= 10.5 MB) and fp32 path =================
template<bool F32>
__device__ void attn_body(const void* x, const void* w_in, const float* b_in,
                          const void* aggrs, float* O) {
    const int h = blockIdx.x;
    const int g = blockIdx.y;
    const int tid = threadIdx.x;
    const int w = tid >> 6, lane = tid & 63, l15 = lane & 15, l4 = lane >> 4;

    __shared__ __align__(16) unsigned short Q_lds[32][72];
    __shared__ __align__(16) unsigned short K_lds[128][72];
    __shared__ __align__(16) unsigned short Vt_lds[64][136];
    __shared__ __align__(16) float S_lds[32][132];
    __shared__ __align__(16) unsigned short P_lds[32][136];

    const long xg = (long)g * 128 * 512;
    const long WqO = (long)(h * 64) * 512;
    const long WkO = (long)(512 + h * 64) * 512;
    const long WvO = (long)(1024 + h * 64) * 512;

    {
        const int d0 = w * 16;
        const float bq = b_in[h * 64 + d0 + l15];
        for (int rt = 0; rt < 2; ++rt) {
            f32x4 acc = {0.f, 0.f, 0.f, 0.f};
#pragma unroll
            for (int kk = 0; kk < 16; ++kk) {
                short8 a = load8<F32>(aggrs, (long)(rt * 16 + l15) * 512 + l4 * 8 + kk * 32);
                short8 b = load8<F32>(w_in, WqO + (long)(d0 + l15) * 512 + l4 * 8 + kk * 32);
                acc = __builtin_amdgcn_mfma_f32_16x16x32_bf16(a, b, acc, 0, 0, 0);
            }
#pragma unroll
            for (int r = 0; r < 4; ++r)
                Q_lds[rt * 16 + l4 * 4 + r][d0 + l15] = f2bf(acc[r] + bq);
        }
    }
    for (int rt = 0; rt < 2; ++rt) {
        const int n0 = w * 32 + rt * 16;
        short8 a[16];
#pragma unroll
        for (int kk = 0; kk < 16; ++kk)
            a[kk] = load8<F32>(x, xg + (long)(n0 + l15) * 512 + l4 * 8 + kk * 32);
        for (int ct = 0; ct < 4; ++ct) {
            const int d0 = ct * 16;
            f32x4 accK = {0.f, 0.f, 0.f, 0.f};
            f32x4 accV = {0.f, 0.f, 0.f, 0.f};
#pragma unroll
            for (int kk = 0; kk < 16; ++kk) {
                short8 bk = load8<F32>(w_in, WkO + (long)(d0 + l15) * 512 + l4 * 8 + kk * 32);
                short8 bv = load8<F32>(w_in, WvO + (long)(d0 + l15) * 512 + l4 * 8 + kk * 32);
                accK = __builtin_amdgcn_mfma_f32_16x16x32_bf16(a[kk], bk, accK, 0, 0, 0);
                accV = __builtin_amdgcn_mfma_f32_16x16x32_bf16(a[kk], bv, accV, 0, 0, 0);
            }
            const float biasK = b_in[512 + h * 64 + d0 + l15];
            const float biasV = b_in[1024 + h * 64 + d0 + l15];
#pragma unroll
            for (int r = 0; r < 4; ++r) {
                const int row = n0 + l4 * 4 + r;
                const int col = d0 + l15;
                K_lds[row][col] = f2bf(accK[r] + biasK);
                Vt_lds[col][row] = f2bf(accV[r] + biasV);
            }
        }
    }
    __syncthreads();
    for (int lt = 0; lt < 2; ++lt) {
        const int l0 = lt * 16;
        short8 qa[2];
        qa[0] = *(const short8*)(&Q_lds[l0 + l15][l4 * 8]);
        qa[1] = *(const short8*)(&Q_lds[l0 + l15][32 + l4 * 8]);
        for (int ct = 0; ct < 2; ++ct) {
            const int n0 = w * 32 + ct * 16;
            f32x4 acc = {0.f, 0.f, 0.f, 0.f};
#pragma unroll
            for (int kk = 0; kk < 2; ++kk) {
                short8 b = *(const short8*)(&K_lds[n0 + l15][kk * 32 + l4 * 8]);
                acc = __builtin_amdgcn_mfma_f32_16x16x32_bf16(qa[kk], b, acc, 0, 0, 0);
            }
#pragma unroll
            for (int r = 0; r < 4; ++r)
                S_lds[l0 + l4 * 4 + r][n0 + l15] = acc[r] * 0.125f;
        }
    }
    __syncthreads();
    {
        const int row = tid >> 3;
        const int j = tid & 7;
        float vals[16];
        float m = -1e30f;
#pragma unroll
        for (int c = 0; c < 16; ++c) {
            vals[c] = S_lds[row][j + c * 8];
            m = fmaxf(m, vals[c]);
        }
#pragma unroll
        for (int s = 1; s < 8; s <<= 1) m = fmaxf(m, __shfl_xor(m, s));
        float sum = 0.f;
#pragma unroll
        for (int c = 0; c < 16; ++c) {
            vals[c] = __expf(vals[c] - m);
            sum += vals[c];
        }
#pragma unroll
        for (int s = 1; s < 8; s <<= 1) sum += __shfl_xor(sum, s);
        const float inv = 1.0f / sum;
#pragma unroll
        for (int c = 0; c < 16; ++c)
            P_lds[row][j + c * 8] = f2bf(vals[c] * inv);
    }
    __syncthreads();
    for (int lt = 0; lt < 2; ++lt) {
        const int l0 = lt * 16;
        const int d0 = w * 16;
        f32x4 acc = {0.f, 0.f, 0.f, 0.f};
#pragma unroll
        for (int kk = 0; kk < 4; ++kk) {
            short8 a = *(const short8*)(&P_lds[l0 + l15][kk * 32 + l4 * 8]);
            short8 b = *(const short8*)(&Vt_lds[d0 + l15][kk * 32 + l4 * 8]);
            acc = __builtin_amdgcn_mfma_f32_16x16x32_bf16(a, b, acc, 0, 0, 0);
        }
#pragma unroll
        for (int r = 0; r < 4; ++r) {
            const int l = l0 + l4 * 4 + r;
            O[(long)(g * 32 + l) * 512 + h * 64 + d0 + l15] = acc[r];
        }
    }
}

__global__ __launch_bounds__(256, 2) void attn_fast(const unsigned short* xb,
                                                    const unsigned short* wb,
                                                    const float* b_in,
                                                    const unsigned short* agb, float* O) {
    attn_body<false>(xb, wb, b_in, agb, O);
}
__global__ __launch_bounds__(256) void attn_f32(const float* x, const float* w_in,
                                                const float* b_in, const float* aggrs,
                                                float* O) {
    attn_body<true>(x, w_in, b_in, aggrs, O);
}

template<bool F32>
__device__ void outproj_body(float* Out, const void* Wo, const float* bo) {
    const int by = blockIdx.x;
    const int tid = threadIdx.x;
    const int w = tid >> 6, lane = tid & 63, l15 = lane & 15, l4 = lane >> 4;

    __shared__ __align__(16) unsigned short O_lds[16][520];

#pragma unroll
    for (int i = 0; i < 4; ++i) {
        int c2 = tid + i * 256;
        int row = c2 >> 6;
        int col = (c2 & 63) * 8;
        const float* src = Out + (long)(by * 16 + row) * 512 + col;
        f32x4 a = *(const f32x4*)src;
        f32x4 b = *(const f32x4*)(src + 4);
        short8 v;
#pragma unroll
        for (int j = 0; j < 4; ++j) { v[j] = (short)f2bf(a[j]); v[4 + j] = (short)f2bf(b[j]); }
        *(short8*)(&O_lds[row][col]) = v;
    }
    __syncthreads();

    short8 a[16];
#pragma unroll
    for (int kk = 0; kk < 16; ++kk)
        a[kk] = *(const short8*)(&O_lds[l15][kk * 32 + l4 * 8]);

    const int cbase = w * 128;
    for (int ct = 0; ct < 8; ++ct) {
        const int col0 = cbase + ct * 16;
        f32x4 acc = {0.f, 0.f, 0.f, 0.f};
#pragma unroll
        for (int kk = 0; kk < 16; ++kk) {
            short8 b = load8<F32>(Wo, (long)(col0 + l15) * 512 + l4 * 8 + kk * 32);
            acc = __builtin_amdgcn_mfma_f32_16x16x32_bf16(a[kk], b, acc, 0, 0, 0);
        }
        const float bias = bo[col0 + l15];
#pragma unroll
        for (int r = 0; r < 4; ++r)
            Out[(long)(by * 16 + l4 * 4 + r) * 512 + col0 + l15] = acc[r] + bias;
    }
}

__global__ __launch_bounds__(256, 2) void outproj_fast(float* Out, const unsigned short* Wob,
                                                       const float* bo) {
    outproj_body<false>(Out, Wob, bo);
}
__global__ __launch_bounds__(256) void outproj_f32(float* Out, const float* Wo,
                                                   const float* bo) {
    outproj_body<true>(Out, Wo, bo);
}

extern "C" void kernel_launch(void* const* d_in, const int* in_sizes, int n_in,
                              void* d_out, int out_size, void* d_ws, size_t ws_size,
                              hipStream_t stream) {
    // Size-based input dispatch — all 7 element counts distinct -> robust to any ordering.
    const int want[7] = {64 * 128 * 512, 64 * 128, 32 * 512, 1536 * 512, 1536, 512 * 512, 512};
    const void* p[7] = {0, 0, 0, 0, 0, 0, 0};
    for (int i = 0; i < n_in && i < 16; ++i)
        for (int j = 0; j < 7; ++j)
            if (in_sizes[i] == want[j] && p[j] == 0) { p[j] = d_in[i]; break; }

    const float* x     = (const float*)p[0];
    const float* aggrs = (const float*)p[2];
    const float* w_in  = (const float*)p[3];
    const float* b_in  = (const float*)p[4];
    const float* Wo    = (const float*)p[5];
    const float* bo    = (const float*)p[6];
    float* out = (float*)d_out;  // (2048,512) fp32

    // ws layout (ushort units)
    const size_t WB = 0, WOB = 786432, AGB = 1048576, XB = 1064960;
    const size_t KVo = 5259264, QSo = 13647872, OHo = 13664256, END = 14712832;

    unsigned short* ws = (unsigned short*)d_ws;
    if (ws_size >= END * 2) {
        convert_kernel<<<dim3(2568), dim3(256), 0, stream>>>(w_in, Wo, aggrs, x, ws + WB);
        qproj2_kernel<<<dim3(8), dim3(256), 0, stream>>>(ws + AGB, ws + WB, b_in, ws + QSo);
        kvgemm_kernel<<<dim3(256), dim3(256), 0, stream>>>(ws + XB, ws + WB, b_in, ws + KVo);
        attn2_kernel<<<dim3(8, 64), dim3(256), 0, stream>>>(ws + KVo, ws + QSo, ws + OHo);
        outproj2_kernel<<<dim3(128), dim3(256), 0, stream>>>(ws + OHo, ws + WOB, bo, out);
    } else if (ws_size >= 10518528) {
        convert_kernel<<<dim3(2568), dim3(256), 0, stream>>>(w_in, Wo, aggrs, x, ws + WB);
        attn_fast<<<dim3(8, 64), dim3(256), 0, stream>>>(ws + XB, ws + WB, b_in, ws + AGB, out);
        outproj_fast<<<dim3(128), dim3(256), 0, stream>>>(out, ws + WOB, bo);
    } else {
        attn_f32<<<dim3(8, 64), dim3(256), 0, stream>>>(x, w_in, b_in, aggrs, out);
        outproj_f32<<<dim3(128), dim3(256), 0, stream>>>(out, Wo, bo);
    }
}